// Round 14
// baseline (78.723 us; speedup 1.0000x reference)
//
#include <hip/hip_runtime.h>

#define LN_EPS 1e-5f

// ---------------------------------------------------------------------------
// Index algebra (verified passing rounds 2-13):
//   F[which][b][g][cc][cs*64+d] = P_{which}[b, s_i, h_i*64+d] + bias
//     s_i = (cc<2 ? 240+8*cc : 8*(cc-2)) + cs,  h_i = g*2 + (cc>>1)
//   Dt[b][gq][gk][cc][cs] = dot64(Fq, Fk) / 8
//   SFK[b][c][d] = 32 * sum_gv FK[b][gv][c>>3][(c&7)*64+d]
//   attn: per (q,k) softmax over 32 c of (vq&vk ? Dt : 0); masked -> 1/32.
//   A[c] = sum_k attn;  ctx[b,q,h*64+d] = sum_c A[c]*SFK[b][c][d].
//   attn_out == 1.0 everywhere.
// MEASURED LEDGER (r10-r13): kG4LN+g=10.26 | kP+kAttn+2g=27.6 | F01(fixed)
//   ~6.3 | boundaries+fixed = 10-18us of 38.7 -> kernel count is 1st-order.
// r14: memset + 3 kernels (kB -> atomicAdd into F; kC -> per-block LDS
// phase inside kAttnF).
// ---------------------------------------------------------------------------

#define FMA4(a, s, v) { (a).x += (s)*(v).x; (a).y += (s)*(v).y; \
                        (a).z += (s)*(v).z; (a).w += (s)*(v).w; }

__device__ __forceinline__ bool sniff_mask_bytes(const unsigned int* m) {
    unsigned int acc = 0;
#pragma unroll
    for (int i = 0; i < 16; ++i) acc |= m[i];
    return acc > 1u;
}

// kAo_at: projection, outer-product split-K, atomicAdd into zeroed F.
// 64 blocks = which(2) x b(2) x mc(16); 512 thr = one output column n each.
__global__ __launch_bounds__(512) void kAo_at(
    const float* __restrict__ Qin, const float* __restrict__ Kin,
    const float* __restrict__ WQ, const float* __restrict__ bQ,
    const float* __restrict__ WK, const float* __restrict__ bK,
    float* __restrict__ F)
{
    __shared__ float Xs[32][36];               // [mm][frow], pad 36
    int bx = blockIdx.x;
    int mc = bx & 15, b = (bx >> 4) & 1, which = bx >> 5;
    int m0 = mc * 32;
    int t = threadIdx.x;                       // n = t

    const float* In = which ? Kin : Qin;
    const float* W  = which ? WK  : WQ;

#pragma unroll
    for (int i = 0; i < 2; ++i) {
        int idx = i * 512 + t;
        int fr = idx >> 5, mm = idx & 31;
        int cc = fr >> 3, cs = fr & 7;
        int srow = (cc < 2) ? (240 + 8 * cc + cs) : (8 * (cc - 2) + cs);
        Xs[mm][fr] = In[(b * 256 + srow) * 512 + m0 + mm];
    }
    __syncthreads();

    int h_i = t >> 6, g = t >> 7;
    int cc0 = (h_i & 1) * 2;                   // wave-uniform
    float acc[16];
#pragma unroll
    for (int j = 0; j < 16; ++j) acc[j] = 0.f;

    const float* wp = W + t;
#pragma unroll 4
    for (int mm = 0; mm < 32; ++mm) {
        float w = wp[(m0 + mm) * 512];         // block-wide coalesced 2KB
        const float4* xp = (const float4*)&Xs[mm][cc0 * 8];
        float4 x0 = xp[0], x1 = xp[1], x2 = xp[2], x3 = xp[3];
        acc[0]  += x0.x * w; acc[1]  += x0.y * w; acc[2]  += x0.z * w; acc[3]  += x0.w * w;
        acc[4]  += x1.x * w; acc[5]  += x1.y * w; acc[6]  += x1.z * w; acc[7]  += x1.w * w;
        acc[8]  += x2.x * w; acc[9]  += x2.y * w; acc[10] += x2.z * w; acc[11] += x2.w * w;
        acc[12] += x3.x * w; acc[13] += x3.y * w; acc[14] += x3.z * w; acc[15] += x3.w * w;
    }

    // bias: n = h_i*64 + d = t for every j (ccj>>1 == h_i&1); add once at mc==0
    float bb = (mc == 0) ? (which ? bK[t] : bQ[t]) : 0.f;
    int d = t & 63;
    int base = ((which * 2 + b) * 4 + g) * 4;
#pragma unroll
    for (int j = 0; j < 16; ++j) {
        int ccj = cc0 + (j >> 3), cs = j & 7;
        atomicAdd(&F[(base + ccj) * 512 + cs * 64 + d], acc[j] + bb);
    }
}

// kAttnF: 1024 blocks x 256 thr.  Phase 0: per-block Dt (b-half, 512 dot64)
// + SFK (2048) into LDS.  Phase 1: wave per (h,q), 2 lanes per k, 16 c each.
__global__ void kAttnF(const float* __restrict__ F, const void* __restrict__ maskp,
                       float* __restrict__ ctx, float* __restrict__ attnp, int fill) {
    __shared__ float Dt_s[512];
    __shared__ float SFK_s[2048];
    __shared__ float aws[4][32];
    int vb = blockIdx.x, t = threadIdx.x;
    if (fill) ((float4*)attnp)[vb * 256 + t] = make_float4(1.f, 1.f, 1.f, 1.f);
    int qb = vb & 63, h = (vb >> 6) & 7, b = vb >> 9;

    // phase 0a: Dt_s[((gq*4+ak)*4+cc)*8+cs] = dot64/8 for this b
#pragma unroll
    for (int rep = 0; rep < 2; ++rep) {
        int eb = rep * 256 + t;
        int gq = eb >> 7, ak = (eb >> 5) & 3, cc = (eb >> 3) & 3, cs = eb & 7;
        const float4* fq = (const float4*)(F + ((b * 4 + gq) * 4 + cc) * 512 + cs * 64);
        const float4* fk = (const float4*)(F + (((2 + b) * 4 + ak) * 4 + cc) * 512 + cs * 64);
        float a = 0.f;
#pragma unroll
        for (int u = 0; u < 16; ++u) {
            float4 x = fq[u], y = fk[u];
            a += x.x * y.x + x.y * y.y + x.z * y.z + x.w * y.w;
        }
        Dt_s[eb] = a * 0.125f;
    }
    // phase 0b: SFK_s[c*64+d] = 32 * sum_gv FK
#pragma unroll
    for (int rep = 0; rep < 8; ++rep) {
        int es = rep * 256 + t;
        int c = es >> 6, d = es & 63;
        float a = 0.f;
#pragma unroll
        for (int gv = 0; gv < 4; ++gv)
            a += F[(((2 + b) * 4 + gv) * 4 + (c >> 3)) * 512 + (c & 7) * 64 + d];
        SFK_s[es] = 32.f * a;
    }
    __syncthreads();

    // phase 1: attention
    int wave = t >> 6, l = t & 63;
    int q = qb * 4 + wave;
    int half = l & 1, klo = l >> 1;
    int g_q = q & 3;
    int i_q = h * 32 + (q >> 3);
    bool up_q = (q & 4) == 0;
    int ak = klo & 3;
    bool up_k = (klo & 4) == 0;

    bool mbytes = sniff_mask_bytes((const unsigned int*)maskp);

    float sq[16];
    const float* Db = Dt_s + (g_q * 4 + ak) * 32 + half * 16;
#pragma unroll
    for (int j = 0; j < 16; ++j) {
        int cc = half * 2 + (j >> 3);
        int row = g_q * 64 + 30 + cc;
        bool vq = up_q ? (i_q >= 256 - row) : (i_q <= 255 - row);
        sq[j] = vq ? Db[j] : 0.f;
    }

    float A[16];
#pragma unroll
    for (int j = 0; j < 16; ++j) A[j] = 0.f;

    int qrow = (b * 256 + q) * 256;
    for (int r = 0; r < 8; ++r) {
        int k = r * 32 + klo;
        bool masked = mbytes ? (((const unsigned char*)maskp)[qrow + k] != 0)
                             : (((const int*)maskp)[qrow + k] != 0);
        if (masked) {
#pragma unroll
            for (int j = 0; j < 16; ++j) A[j] += 0.03125f;
            continue;
        }
        int i_k = h * 32 + (k >> 3);
        float s[16];
        float mx = -1e30f;
#pragma unroll
        for (int j = 0; j < 16; ++j) {
            int cc = half * 2 + (j >> 3);
            int row = ak * 64 + 30 + cc;
            bool vk = up_k ? (i_k >= 256 - row) : (i_k <= 255 - row);
            s[j] = vk ? sq[j] : 0.f;
            mx = fmaxf(mx, s[j]);
        }
        mx = fmaxf(mx, __shfl_xor(mx, 1));
        float den = 0.f;
#pragma unroll
        for (int j = 0; j < 16; ++j) { s[j] = __expf(s[j] - mx); den += s[j]; }
        den += __shfl_xor(den, 1);
        float inv = 1.f / den;
#pragma unroll
        for (int j = 0; j < 16; ++j) A[j] += s[j] * inv;
    }

#pragma unroll
    for (int off = 2; off < 64; off <<= 1) {
#pragma unroll
        for (int j = 0; j < 16; ++j) A[j] += __shfl_xor(A[j], off);
    }

    float* aw = aws[wave];
    if (l < 2) {
#pragma unroll
        for (int j = 0; j < 16; ++j) aw[l * 16 + j] = A[j];
    }
    float acc = 0.f;
#pragma unroll
    for (int c = 0; c < 32; ++c) acc += aw[c] * SFK_s[c * 64 + l];
    ctx[(b * 256 + q) * 512 + h * 64 + l] = acc;
}

// kG4LN: outer-product Wo GEMM + bias + residual + LayerNorm, fused.
// 128 blocks x 512 thr; block = 4 output rows.  (r9 version.)
__global__ __launch_bounds__(512) void kG4LN(
    const float* __restrict__ ctx, const float* __restrict__ Wo,
    const float* __restrict__ bo, const float* __restrict__ Qin,
    const float* __restrict__ gamma, const float* __restrict__ beta,
    float* __restrict__ out)
{
    __shared__ float  Cl[4][512];
    __shared__ float4 red4[8][4][64];
    __shared__ float  red2[8][2];

    int t = threadIdx.x, r0 = blockIdx.x * 4;
    int w = t >> 6, l = t & 63;

    ((float4*)Cl)[t] = ((const float4*)&ctx[r0 * 512])[t];
    __syncthreads();

    const float4* WoV = (const float4*)Wo;
    const float4* pA = WoV + (size_t)(w * 64) * 128 + l;
    const float4* pB = pA + 64;
    float4 a0A = {0,0,0,0}, a1A = {0,0,0,0}, a2A = {0,0,0,0}, a3A = {0,0,0,0};
    float4 a0B = {0,0,0,0}, a1B = {0,0,0,0}, a2B = {0,0,0,0}, a3B = {0,0,0,0};
    int m0 = w * 64;
    float4 wA = pA[0], wB = pB[0];
#pragma unroll 4
    for (int mm = 0; mm < 63; ++mm) {
        float4 nA = pA[(mm + 1) * 128];
        float4 nB = pB[(mm + 1) * 128];
        float s0 = Cl[0][m0 + mm], s1 = Cl[1][m0 + mm];
        float s2 = Cl[2][m0 + mm], s3 = Cl[3][m0 + mm];
        FMA4(a0A, s0, wA); FMA4(a1A, s1, wA); FMA4(a2A, s2, wA); FMA4(a3A, s3, wA);
        FMA4(a0B, s0, wB); FMA4(a1B, s1, wB); FMA4(a2B, s2, wB); FMA4(a3B, s3, wB);
        wA = nA; wB = nB;
    }
    {
        float s0 = Cl[0][m0 + 63], s1 = Cl[1][m0 + 63];
        float s2 = Cl[2][m0 + 63], s3 = Cl[3][m0 + 63];
        FMA4(a0A, s0, wA); FMA4(a1A, s1, wA); FMA4(a2A, s2, wA); FMA4(a3A, s3, wA);
        FMA4(a0B, s0, wB); FMA4(a1B, s1, wB); FMA4(a2B, s2, wB); FMA4(a3B, s3, wB);
    }

    red4[w][0][l] = a0A; red4[w][1][l] = a1A; red4[w][2][l] = a2A; red4[w][3][l] = a3A;
    __syncthreads();
    if (t < 256) {
        int r = t >> 6, c4 = t & 63;
        float4 s = red4[0][r][c4];
#pragma unroll
        for (int w2 = 1; w2 < 8; ++w2) {
            float4 v = red4[w2][r][c4];
            s.x += v.x; s.y += v.y; s.z += v.z; s.w += v.w;
        }
        float4 bb = ((const float4*)bo)[c4];
        float4 qq = ((const float4*)Qin)[(r0 + r) * 128 + c4];
        s.x += bb.x + qq.x; s.y += bb.y + qq.y;
        s.z += bb.z + qq.z; s.w += bb.w + qq.w;
        *(float4*)&Cl[r][c4 * 4] = s;
    }
    __syncthreads();
    red4[w][0][l] = a0B; red4[w][1][l] = a1B; red4[w][2][l] = a2B; red4[w][3][l] = a3B;
    __syncthreads();
    if (t < 256) {
        int r = t >> 6, c4 = t & 63;
        float4 s = red4[0][r][c4];
#pragma unroll
        for (int w2 = 1; w2 < 8; ++w2) {
            float4 v = red4[w2][r][c4];
            s.x += v.x; s.y += v.y; s.z += v.z; s.w += v.w;
        }
        float4 bb = ((const float4*)bo)[64 + c4];
        float4 qq = ((const float4*)Qin)[(r0 + r) * 128 + 64 + c4];
        s.x += bb.x + qq.x; s.y += bb.y + qq.y;
        s.z += bb.z + qq.z; s.w += bb.w + qq.w;
        *(float4*)&Cl[r][256 + c4 * 4] = s;
    }
    __syncthreads();

    int r = t >> 7, c = t & 127;
    float v0 = Cl[r][c], v1 = Cl[r][c + 128], v2 = Cl[r][c + 256], v3 = Cl[r][c + 384];
    float s1 = v0 + v1 + v2 + v3;
    float s2 = v0 * v0 + v1 * v1 + v2 * v2 + v3 * v3;
#pragma unroll
    for (int off = 1; off < 64; off <<= 1) {
        s1 += __shfl_xor(s1, off);
        s2 += __shfl_xor(s2, off);
    }
    if (l == 0) { red2[w][0] = s1; red2[w][1] = s2; }
    __syncthreads();
    float tot1 = red2[2 * r][0] + red2[2 * r + 1][0];
    float tot2 = red2[2 * r][1] + red2[2 * r + 1][1];
    float mu = tot1 * (1.f / 512.f);
    float var = tot2 * (1.f / 512.f) - mu * mu;
    float rs = rsqrtf(var + LN_EPS);
    float* op = out + (r0 + r) * 512;
    op[c]       = (v0 - mu) * rs * gamma[c]       + beta[c];
    op[c + 128] = (v1 - mu) * rs * gamma[c + 128] + beta[c + 128];
    op[c + 256] = (v2 - mu) * rs * gamma[c + 256] + beta[c + 256];
    op[c + 384] = (v3 - mu) * rs * gamma[c + 384] + beta[c + 384];
}

// plan-B only: restore attn_out region (which hosted scratch) to 1.0
__global__ void k5_fill(float* __restrict__ p, int n) {
    int i = (blockIdx.x * 256 + threadIdx.x) * 4;
    float4 one = make_float4(1.f, 1.f, 1.f, 1.f);
    for (; i < n; i += gridDim.x * 256 * 4) *(float4*)(p + i) = one;
}

extern "C" void kernel_launch(void* const* d_in, const int* in_sizes, int n_in,
                              void* d_out, int out_size, void* d_ws, size_t ws_size,
                              hipStream_t stream) {
    (void)in_sizes; (void)n_in; (void)out_size;
    const float* Qin  = (const float*)d_in[0];
    const float* Kin  = (const float*)d_in[1];
    const void*  mask = d_in[3];
    const float* WQ   = (const float*)d_in[4];
    const float* bQ   = (const float*)d_in[5];
    const float* WK   = (const float*)d_in[6];
    const float* bK   = (const float*)d_in[7];
    const float* Wo   = (const float*)d_in[10];
    const float* bo   = (const float*)d_in[11];
    const float* gamma= (const float*)d_in[12];
    const float* beta = (const float*)d_in[13];

    float* out   = (float*)d_out;
    float* attnp = out + 262144;                  // 1,048,576 floats (output 1)

    const size_t NEED = 294912ull * sizeof(float);
    int fill;
    float *F, *ctx;
    if (ws_size >= NEED) {                        // plan A
        F   = (float*)d_ws;                       // 32768
        ctx = (float*)d_ws + 32768;               // 262144
        fill = 1;
    } else {                                      // plan B (inside attn_out)
        F   = attnp + 524288;
        ctx = attnp + 786432;
        fill = 0;
    }

    hipMemsetAsync(F, 0, 32768 * sizeof(float), stream);
    kAo_at <<<dim3(64),   dim3(512), 0, stream>>>(Qin, Kin, WQ, bQ, WK, bK, F);
    kAttnF <<<dim3(1024), dim3(256), 0, stream>>>(F, mask, ctx, attnp, fill);
    kG4LN  <<<dim3(128),  dim3(512), 0, stream>>>(ctx, Wo, bo, Qin, gamma, beta, out);
    if (!fill) k5_fill<<<dim3(256), dim3(256), 0, stream>>>(attnp, 1048576);
}

// Round 15
// 44.499 us; speedup vs baseline: 1.7691x; 1.7691x over previous
//
#include <hip/hip_runtime.h>

#define LN_EPS 1e-5f

// ---------------------------------------------------------------------------
// Index algebra (verified passing rounds 2-14):
//   F[which][b][g][cc][cs*64+d] = P_{which}[b, s_i, h_i*64+d] + bias
//     s_i = (cc<2 ? 240+8*cc : 8*(cc-2)) + cs,  h_i = g*2 + (cc>>1)
//   Dt[b][gq][gk][cc][cs] = dot64(Fq, Fk) / 8
//   SFK[b][c][d] = 32 * sum_gv FK[b][gv][c>>3][(c&7)*64+d]
//   attn: per (q,k) softmax over 32 c of (vq&vk ? Dt : 0); masked -> 1/32.
//   A[c] = sum_k attn;  ctx[b,q,h*64+d] = sum_c A[c]*SFK[b][c][d].
//   attn_out == 1.0 everywhere.
// MEASURED LEDGER: kG4LN(r9,1wave/SIMD)=8.8 (L2 floor 3.7) | kAttn~6.5 |
//   kAo~2.5 | kC~1 | fixed~6.3 | gaps ~1.5-2 each.
// r14 LESSON (56us kAttnF): never replicate L2-heavy table compute per
// block, and never per-lane-walk divergent bases. Tables stay in kC.
// r15: kG4LN2 = 16 waves/block (4/SIMD) to hide latency at same traffic.
// ---------------------------------------------------------------------------

#define FMA4(a, s, v) { (a).x += (s)*(v).x; (a).y += (s)*(v).y; \
                        (a).z += (s)*(v).z; (a).w += (s)*(v).w; }

__device__ __forceinline__ bool sniff_mask_bytes(const unsigned int* m) {
    unsigned int acc = 0;
#pragma unroll
    for (int i = 0; i < 16; ++i) acc |= m[i];
    return acc > 1u;
}

// kAo_at: projection, outer-product split-K, atomicAdd into zeroed F.
// 64 blocks = which(2) x b(2) x mc(16); 512 thr = one output column n each.
__global__ __launch_bounds__(512) void kAo_at(
    const float* __restrict__ Qin, const float* __restrict__ Kin,
    const float* __restrict__ WQ, const float* __restrict__ bQ,
    const float* __restrict__ WK, const float* __restrict__ bK,
    float* __restrict__ F)
{
    __shared__ float Xs[32][36];
    int bx = blockIdx.x;
    int mc = bx & 15, b = (bx >> 4) & 1, which = bx >> 5;
    int m0 = mc * 32;
    int t = threadIdx.x;

    const float* In = which ? Kin : Qin;
    const float* W  = which ? WK  : WQ;

#pragma unroll
    for (int i = 0; i < 2; ++i) {
        int idx = i * 512 + t;
        int fr = idx >> 5, mm = idx & 31;
        int cc = fr >> 3, cs = fr & 7;
        int srow = (cc < 2) ? (240 + 8 * cc + cs) : (8 * (cc - 2) + cs);
        Xs[mm][fr] = In[(b * 256 + srow) * 512 + m0 + mm];
    }
    __syncthreads();

    int h_i = t >> 6, g = t >> 7;
    int cc0 = (h_i & 1) * 2;
    float acc[16];
#pragma unroll
    for (int j = 0; j < 16; ++j) acc[j] = 0.f;

    const float* wp = W + t;
#pragma unroll 4
    for (int mm = 0; mm < 32; ++mm) {
        float w = wp[(m0 + mm) * 512];
        const float4* xp = (const float4*)&Xs[mm][cc0 * 8];
        float4 x0 = xp[0], x1 = xp[1], x2 = xp[2], x3 = xp[3];
        acc[0]  += x0.x * w; acc[1]  += x0.y * w; acc[2]  += x0.z * w; acc[3]  += x0.w * w;
        acc[4]  += x1.x * w; acc[5]  += x1.y * w; acc[6]  += x1.z * w; acc[7]  += x1.w * w;
        acc[8]  += x2.x * w; acc[9]  += x2.y * w; acc[10] += x2.z * w; acc[11] += x2.w * w;
        acc[12] += x3.x * w; acc[13] += x3.y * w; acc[14] += x3.z * w; acc[15] += x3.w * w;
    }

    float bb = (mc == 0) ? (which ? bK[t] : bQ[t]) : 0.f;
    int d = t & 63;
    int base = ((which * 2 + b) * 4 + g) * 4;
#pragma unroll
    for (int j = 0; j < 16; ++j) {
        int ccj = cc0 + (j >> 3), cs = j & 7;
        atomicAdd(&F[(base + ccj) * 512 + cs * 64 + d], acc[j] + bb);
    }
}

// kC: Dt (8-lane dots + shfl) and SFK (pre-scaled x32).  48 blocks x 256 thr.
__global__ void kC_dtab_sfk(const float* __restrict__ F, float* __restrict__ Dt,
                            float* __restrict__ SFK) {
    int slot = blockIdx.x * 256 + threadIdx.x;
    if (slot < 8192) {
        int part = slot & 7, e = slot >> 3;
        int cs = e & 7, cc = (e >> 3) & 3, gk = (e >> 5) & 3,
            gq = (e >> 7) & 3, b = (e >> 9) & 1;
        const float* fq = F + ((b * 4 + gq) * 4 + cc) * 512 + cs * 64 + part * 8;
        const float* fk = F + (((2 + b) * 4 + gk) * 4 + cc) * 512 + cs * 64 + part * 8;
        float a = 0.f;
#pragma unroll
        for (int u = 0; u < 8; ++u) a += fq[u] * fk[u];
        a += __shfl_xor(a, 1);
        a += __shfl_xor(a, 2);
        a += __shfl_xor(a, 4);
        if (part == 0) Dt[e] = a * 0.125f;
    } else {
        int e = slot - 8192;
        int d = e & 63, c = (e >> 6) & 31, b = e >> 11;
        float a = 0.f;
#pragma unroll
        for (int gv = 0; gv < 4; ++gv)
            a += F[(((2 + b) * 4 + gv) * 4 + (c >> 3)) * 512 + (c & 7) * 64 + d];
        SFK[e] = 32.f * a;
    }
}

// kAttn: 1024 blocks x 256 thr.  Wave per (h,q); 2 lanes per k, 16 c each.
// (r13 version — Dt/SFK read from global/L2, measured-OK.)
__global__ void kAttn(const float* __restrict__ Dt, const void* __restrict__ maskp,
                      const float* __restrict__ SFK, float* __restrict__ ctx,
                      float* __restrict__ attnp, int fill) {
    __shared__ float aws[4][32];
    int vb = blockIdx.x, t = threadIdx.x;
    if (fill) ((float4*)attnp)[vb * 256 + t] = make_float4(1.f, 1.f, 1.f, 1.f);
    int qb = vb & 63, h = (vb >> 6) & 7, b = vb >> 9;
    int wave = t >> 6, l = t & 63;
    int q = qb * 4 + wave;
    int half = l & 1, klo = l >> 1;
    int g_q = q & 3;
    int i_q = h * 32 + (q >> 3);
    bool up_q = (q & 4) == 0;
    int ak = klo & 3;
    bool up_k = (klo & 4) == 0;

    bool mbytes = sniff_mask_bytes((const unsigned int*)maskp);

    float sq[16];
    const float* Db = Dt + ((b * 4 + g_q) * 4 + ak) * 32 + half * 16;
#pragma unroll
    for (int j = 0; j < 16; ++j) {
        int cc = half * 2 + (j >> 3);
        int row = g_q * 64 + 30 + cc;
        bool vq = up_q ? (i_q >= 256 - row) : (i_q <= 255 - row);
        sq[j] = vq ? Db[j] : 0.f;
    }

    float A[16];
#pragma unroll
    for (int j = 0; j < 16; ++j) A[j] = 0.f;

    int qrow = (b * 256 + q) * 256;
    for (int r = 0; r < 8; ++r) {
        int k = r * 32 + klo;
        bool masked = mbytes ? (((const unsigned char*)maskp)[qrow + k] != 0)
                             : (((const int*)maskp)[qrow + k] != 0);
        if (masked) {
#pragma unroll
            for (int j = 0; j < 16; ++j) A[j] += 0.03125f;
            continue;
        }
        int i_k = h * 32 + (k >> 3);
        float s[16];
        float mx = -1e30f;
#pragma unroll
        for (int j = 0; j < 16; ++j) {
            int cc = half * 2 + (j >> 3);
            int row = ak * 64 + 30 + cc;
            bool vk = up_k ? (i_k >= 256 - row) : (i_k <= 255 - row);
            s[j] = vk ? sq[j] : 0.f;
            mx = fmaxf(mx, s[j]);
        }
        mx = fmaxf(mx, __shfl_xor(mx, 1));
        float den = 0.f;
#pragma unroll
        for (int j = 0; j < 16; ++j) { s[j] = __expf(s[j] - mx); den += s[j]; }
        den += __shfl_xor(den, 1);
        float inv = 1.f / den;
#pragma unroll
        for (int j = 0; j < 16; ++j) A[j] += s[j] * inv;
    }

#pragma unroll
    for (int off = 2; off < 64; off <<= 1) {
#pragma unroll
        for (int j = 0; j < 16; ++j) A[j] += __shfl_xor(A[j], off);
    }

    float* aw = aws[wave];
    if (l < 2) {
#pragma unroll
        for (int j = 0; j < 16; ++j) aw[l * 16 + j] = A[j];
    }
    float acc = 0.f;
    const float* S = SFK + b * 2048;
#pragma unroll
    for (int c = 0; c < 32; ++c) acc += aw[c] * S[c * 64 + l];
    ctx[(b * 256 + q) * 512 + h * 64 + l] = acc;
}

// kG4LN2: outer-product Wo GEMM + bias + residual + LN, 1024 thr / 16 waves.
// 128 blocks; block = 4 rows.  Wave w: m in [ (w>>1)*64, +64 ), col-half w&1.
// 4 waves/SIMD hides L2 latency (r9's 1 wave/SIMD was the 8.8us cause).
__global__ __launch_bounds__(1024) void kG4LN2(
    const float* __restrict__ ctx, const float* __restrict__ Wo,
    const float* __restrict__ bo, const float* __restrict__ Qin,
    const float* __restrict__ gamma, const float* __restrict__ beta,
    float* __restrict__ out)
{
    __shared__ float  Cl[4][512];          // ctx rows -> reused as y tile
    __shared__ float4 red4[8][4][64];      // 32 KB partials (one col-half)
    __shared__ float  red2[4][4][2];

    int t = threadIdx.x, r0 = blockIdx.x * 4;
    int w = t >> 6, l = t & 63;
    int mc = w >> 1, h2 = w & 1;
    int m0 = mc * 64;

    if (t < 512) ((float4*)Cl)[t] = ((const float4*)&ctx[r0 * 512])[t];
    __syncthreads();

    const float4* p = (const float4*)Wo + (size_t)m0 * 128 + h2 * 64 + l;
    float4 a0 = {0,0,0,0}, a1 = {0,0,0,0}, a2 = {0,0,0,0}, a3 = {0,0,0,0};
    float4 wv = p[0];
#pragma unroll 4
    for (int mm = 0; mm < 63; ++mm) {
        float4 nx = p[(mm + 1) * 128];
        float s0 = Cl[0][m0 + mm], s1 = Cl[1][m0 + mm];
        float s2 = Cl[2][m0 + mm], s3 = Cl[3][m0 + mm];
        FMA4(a0, s0, wv); FMA4(a1, s1, wv); FMA4(a2, s2, wv); FMA4(a3, s3, wv);
        wv = nx;
    }
    {
        float s0 = Cl[0][m0 + 63], s1 = Cl[1][m0 + 63];
        float s2 = Cl[2][m0 + 63], s3 = Cl[3][m0 + 63];
        FMA4(a0, s0, wv); FMA4(a1, s1, wv); FMA4(a2, s2, wv); FMA4(a3, s3, wv);
    }
    __syncthreads();                        // all Cl reads complete

    // pass 0: col-half 0
    if (h2 == 0) { red4[mc][0][l] = a0; red4[mc][1][l] = a1;
                   red4[mc][2][l] = a2; red4[mc][3][l] = a3; }
    __syncthreads();
    if (t < 256) {
        int r = t >> 6, c4 = t & 63;
        float4 s = red4[0][r][c4];
#pragma unroll
        for (int u = 1; u < 8; ++u) {
            float4 v = red4[u][r][c4];
            s.x += v.x; s.y += v.y; s.z += v.z; s.w += v.w;
        }
        float4 bb = ((const float4*)bo)[c4];
        float4 qq = ((const float4*)Qin)[(r0 + r) * 128 + c4];
        s.x += bb.x + qq.x; s.y += bb.y + qq.y;
        s.z += bb.z + qq.z; s.w += bb.w + qq.w;
        *(float4*)&Cl[r][c4 * 4] = s;
    }
    __syncthreads();
    // pass 1: col-half 1
    if (h2 == 1) { red4[mc][0][l] = a0; red4[mc][1][l] = a1;
                   red4[mc][2][l] = a2; red4[mc][3][l] = a3; }
    __syncthreads();
    if (t < 256) {
        int r = t >> 6, c4 = t & 63;
        float4 s = red4[0][r][c4];
#pragma unroll
        for (int u = 1; u < 8; ++u) {
            float4 v = red4[u][r][c4];
            s.x += v.x; s.y += v.y; s.z += v.z; s.w += v.w;
        }
        float4 bb = ((const float4*)bo)[64 + c4];
        float4 qq = ((const float4*)Qin)[(r0 + r) * 128 + 64 + c4];
        s.x += bb.x + qq.x; s.y += bb.y + qq.y;
        s.z += bb.z + qq.z; s.w += bb.w + qq.w;
        *(float4*)&Cl[r][256 + c4 * 4] = s;
    }
    __syncthreads();

    // LayerNorm: r = t>>8 (4 waves per row), cols cc and cc+256
    int r = t >> 8, cc = t & 255;
    float y0 = Cl[r][cc], y1 = Cl[r][cc + 256];
    float s1 = y0 + y1, s2 = y0 * y0 + y1 * y1;
#pragma unroll
    for (int off = 1; off < 64; off <<= 1) {
        s1 += __shfl_xor(s1, off);
        s2 += __shfl_xor(s2, off);
    }
    if (l == 0) { red2[r][w & 3][0] = s1; red2[r][w & 3][1] = s2; }
    __syncthreads();
    float tot1 = red2[r][0][0] + red2[r][1][0] + red2[r][2][0] + red2[r][3][0];
    float tot2 = red2[r][0][1] + red2[r][1][1] + red2[r][2][1] + red2[r][3][1];
    float mu = tot1 * (1.f / 512.f);
    float var = tot2 * (1.f / 512.f) - mu * mu;
    float rs = rsqrtf(var + LN_EPS);
    float* op = out + (r0 + r) * 512;
    op[cc]       = (y0 - mu) * rs * gamma[cc]       + beta[cc];
    op[cc + 256] = (y1 - mu) * rs * gamma[cc + 256] + beta[cc + 256];
}

// plan-B only: restore attn_out region (which hosted scratch) to 1.0
__global__ void k5_fill(float* __restrict__ p, int n) {
    int i = (blockIdx.x * 256 + threadIdx.x) * 4;
    float4 one = make_float4(1.f, 1.f, 1.f, 1.f);
    for (; i < n; i += gridDim.x * 256 * 4) *(float4*)(p + i) = one;
}

extern "C" void kernel_launch(void* const* d_in, const int* in_sizes, int n_in,
                              void* d_out, int out_size, void* d_ws, size_t ws_size,
                              hipStream_t stream) {
    (void)in_sizes; (void)n_in; (void)out_size;
    const float* Qin  = (const float*)d_in[0];
    const float* Kin  = (const float*)d_in[1];
    const void*  mask = d_in[3];
    const float* WQ   = (const float*)d_in[4];
    const float* bQ   = (const float*)d_in[5];
    const float* WK   = (const float*)d_in[6];
    const float* bK   = (const float*)d_in[7];
    const float* Wo   = (const float*)d_in[10];
    const float* bo   = (const float*)d_in[11];
    const float* gamma= (const float*)d_in[12];
    const float* beta = (const float*)d_in[13];

    float* out   = (float*)d_out;
    float* attnp = out + 262144;                  // 1,048,576 floats (output 1)

    const size_t NEED = 300032ull * sizeof(float);
    int fill;
    float *F, *Dt, *SFK, *ctx;
    if (ws_size >= NEED) {                        // plan A
        float* ws = (float*)d_ws;
        F   = ws;                                 // 32768
        Dt  = ws + 32768;                         // 1024
        SFK = ws + 33792;                         // 4096
        ctx = ws + 37888;                         // 262144
        fill = 1;
    } else {                                      // plan B (inside attn_out)
        F   = attnp + 524288;
        Dt  = attnp + 557056;
        SFK = attnp + 558080;
        ctx = attnp + 786432;
        fill = 0;
    }

    hipMemsetAsync(F, 0, 32768 * sizeof(float), stream);
    kAo_at     <<<dim3(64),   dim3(512),  0, stream>>>(Qin, Kin, WQ, bQ, WK, bK, F);
    kC_dtab_sfk<<<dim3(48),   dim3(256),  0, stream>>>(F, Dt, SFK);
    kAttn      <<<dim3(1024), dim3(256),  0, stream>>>(Dt, mask, SFK, ctx, attnp, fill);
    kG4LN2     <<<dim3(128),  dim3(1024), 0, stream>>>(ctx, Wo, bo, Qin, gamma, beta, out);
    if (!fill) k5_fill<<<dim3(256), dim3(256), 0, stream>>>(attnp, 1048576);
}